// Round 7
// baseline (720.110 us; speedup 1.0000x reference)
//
#include <hip/hip_runtime.h>
#include <cstdint>
#include <cstddef>

#define BS_   128
#define MSL_  128
#define D_    768
#define NH_   12
#define DH_   64
#define DI_   3072
#define ROWS_ (BS_ * MSL_)   // 16384

using bf16x8 = __attribute__((ext_vector_type(8))) __bf16;
using f32x4  = __attribute__((ext_vector_type(4))) float;

// Exact RNE f32 -> bf16 bits.
static __device__ __forceinline__ uint16_t f2b(float f) {
    uint32_t u = __builtin_bit_cast(uint32_t, f);
    u += 0x7fffu + ((u >> 16) & 1u);
    return (uint16_t)(u >> 16);
}
static __device__ __forceinline__ float b2f(uint16_t h) {
    uint32_t u = ((uint32_t)h) << 16;
    return __builtin_bit_cast(float, u);
}

__global__ __launch_bounds__(256)
void cvt_f32_bf16(const float* __restrict__ in, uint16_t* __restrict__ out, int n4) {
    int i = blockIdx.x * blockDim.x + threadIdx.x;
    if (i >= n4) return;
    float4 v = ((const float4*)in)[i];
    ushort4 o;
    o.x = f2b(v.x); o.y = f2b(v.y); o.z = f2b(v.z); o.w = f2b(v.w);
    ((ushort4*)out)[i] = o;
}

// async global->LDS, 16B per lane. LDS dest is wave-uniform base (+lane*16 in HW).
static __device__ __forceinline__ void gload16(const uint16_t* g, uint16_t* l) {
    __builtin_amdgcn_global_load_lds(
        (__attribute__((address_space(1))) void*)(uintptr_t)g,
        (__attribute__((address_space(3))) void*)(uintptr_t)l,
        16, 0, 0);
}

// 16 MFMA = one C-quadrant (4 i-frags x 2 j-frags x K=64), setprio-wrapped (T5).
#define MFMA_Q(AR, BR, IOFF, JOFF)  do {                                        \
    __builtin_amdgcn_s_setprio(1);                                              \
    _Pragma("unroll")                                                           \
    for (int i_ = 0; i_ < 4; ++i_) {                                            \
        _Pragma("unroll")                                                       \
        for (int j_ = 0; j_ < 2; ++j_) {                                        \
            acc[(IOFF)+i_][(JOFF)+j_] = __builtin_amdgcn_mfma_f32_16x16x32_bf16( \
                AR[i_][0], BR[j_][0], acc[(IOFF)+i_][(JOFF)+j_], 0, 0, 0);      \
            acc[(IOFF)+i_][(JOFF)+j_] = __builtin_amdgcn_mfma_f32_16x16x32_bf16( \
                AR[i_][1], BR[j_][1], acc[(IOFF)+i_][(JOFF)+j_], 0, 0, 0);      \
        }                                                                       \
    }                                                                           \
    __builtin_amdgcn_s_setprio(0); } while (0)

#define PH_SYNC_RD() do { __builtin_amdgcn_s_barrier();                         \
    asm volatile("s_waitcnt lgkmcnt(0)" ::: "memory");                          \
    __builtin_amdgcn_sched_barrier(0); } while (0)
#define PH_SYNC()    do { __builtin_amdgcn_s_barrier();                         \
    __builtin_amdgcn_sched_barrier(0); } while (0)
#define PH_END()     do { __builtin_amdgcn_s_barrier();                         \
    __builtin_amdgcn_sched_barrier(0); } while (0)

// ---------------- bf16 MFMA GEMM: C = epi(A @ B^T + bias) ----------------
// A: [M][K] bf16 row-major, B: [N][K] bf16 row-major, C: [M][N] bf16.
// EPI: 0 = +bias; 1 = (+bias)*scale+shift; 2 = relu(+bias)
// 256x256 tile, BK=64, 8 waves (2Mx4N), per-wave 128x64 output.
// 8-phase counted-vmcnt schedule (T3+T4+T5), 2 K-tiles per iteration:
//   phases 1-4 compute tile t (buf0) as 4 quadrants; 5-8 compute t+1 (buf1).
//   ds_reads front-loaded to the first 2 phases of each tile -> the tile's LDS
//   is fully read after its 2nd phase, so later phases may stage into it.
//   One half-tile stage per phase, 3-unit lead: p1,p2: t+1.B0,B1 | p3..p6:
//   t+2.A0,A1,B0,B1 | p7,p8: t+3.A0,A1.  vmcnt(4) at phases 4 & 8 only
//   (the needed tile's 8 loads are the oldest of <=12 outstanding); vmcnt(0)
//   only in the last iteration.  NT = K/64 is even for K in {768, 3072}.
// LDS chunk swizzle: phys16Bchunk = logical ^ (row&7), on BOTH the global
// source and the ds_read (involution, rule #21) -> <=2-way (free, 0 measured).
template<int EPI>
__global__ __launch_bounds__(512, 1)
void gemm_bf16(const uint16_t* __restrict__ A, const uint16_t* __restrict__ B,
               const float* __restrict__ bias, const float* __restrict__ scale,
               const float* __restrict__ shift, uint16_t* __restrict__ C,
               int M, int N, int K, int gx)
{
    __shared__ __align__(16) uint16_t As[2][256 * 64];
    __shared__ __align__(16) uint16_t Bs[2][256 * 64];
    const int tid  = threadIdx.x;
    const int lane = tid & 63;
    const int m_   = lane & 15;
    const int kg   = lane >> 4;           // k-group 0..3 (8 bf16 each)
    const int w    = tid >> 6;
    const int wr   = w >> 2;              // 0..1  (A half = wr)
    const int wc   = w & 3;               // 0..3  (B 64-row strip)

    // T1 bijective XCD swizzle (nwg % 8 == 0 for all grids used here).
    const int nwg = gridDim.x;
    const int q   = nwg >> 3;
    const int wg  = (blockIdx.x & 7) * q + (blockIdx.x >> 3);
    const int m0  = (wg / gx) * 256;
    const int n0  = (wg % gx) * 256;

    f32x4 acc[8][4] = {};

    // ds_read chunk ids (depend only on lane): chunk = (kk*4+kg) ^ (m_&7)
    int chx[2];
    chx[0] = (kg) ^ (m_ & 7);
    chx[1] = (4 + kg) ^ (m_ & 7);

    // Staging map: tile = 256 rows x 8 chunks(16B) = 2048 chunks; 4/thread.
    // it 0,1 -> rows 0..127 (half 0); it 2,3 -> rows 128..255 (half 1).
    int srow[4], ssl[4], sbase[4];
#pragma unroll
    for (int it = 0; it < 4; ++it) {
        const int c = it * 512 + tid;
        srow[it]  = c >> 3;
        ssl[it]   = (c & 7) ^ (srow[it] & 7);
        sbase[it] = (it * 512 + (tid & 448)) * 8;   // wave-uniform chunk base
    }
    auto stageA = [&](int buf, int k0, int half) {
        const int it0 = half * 2, it1 = it0 + 1;
        gload16(A + (size_t)(m0 + srow[it0]) * K + k0 + ssl[it0] * 8, &As[buf][sbase[it0]]);
        gload16(A + (size_t)(m0 + srow[it1]) * K + k0 + ssl[it1] * 8, &As[buf][sbase[it1]]);
    };
    auto stageB = [&](int buf, int k0, int half) {
        const int it0 = half * 2, it1 = it0 + 1;
        gload16(B + (size_t)(n0 + srow[it0]) * K + k0 + ssl[it0] * 8, &Bs[buf][sbase[it0]]);
        gload16(B + (size_t)(n0 + srow[it1]) * K + k0 + ssl[it1] * 8, &Bs[buf][sbase[it1]]);
    };

    bf16x8 aLo[4][2], aHi[4][2], bLo[2][2], bHi[2][2];
    auto rdA = [&](const uint16_t* S, int half, bf16x8 (&dst)[4][2]) {
#pragma unroll
        for (int i = 0; i < 4; ++i) {
            const int row = wr * 128 + half * 64 + i * 16 + m_;
#pragma unroll
            for (int kk = 0; kk < 2; ++kk)
                dst[i][kk] = *reinterpret_cast<const bf16x8*>(
                    &S[row * 64 + chx[kk] * 8]);
        }
    };
    auto rdB = [&](const uint16_t* S, int jp, bf16x8 (&dst)[2][2]) {
#pragma unroll
        for (int j = 0; j < 2; ++j) {
            const int row = wc * 64 + (jp * 2 + j) * 16 + m_;
#pragma unroll
            for (int kk = 0; kk < 2; ++kk)
                dst[j][kk] = *reinterpret_cast<const bf16x8*>(
                    &S[row * 64 + chx[kk] * 8]);
        }
    };

    // ---- prologue: tile0 full + tile1 A-halves; gate tile0 ----
    stageA(0, 0, 0); stageA(0, 0, 1); stageB(0, 0, 0); stageB(0, 0, 1);
    stageA(1, 64, 0); stageA(1, 64, 1);
    asm volatile("s_waitcnt vmcnt(4)" ::: "memory");   // tile0's 8 loads landed
    __builtin_amdgcn_s_barrier();
    __builtin_amdgcn_sched_barrier(0);

    const int NT = K >> 6;   // even
    for (int t = 0; t < NT; t += 2) {
        const bool last = (t + 2 >= NT);
        const int k1 = (t + 1) << 6, k2 = (t + 2) << 6, k3 = (t + 3) << 6;

        // ---- phase 1: tile t quadrant (0,0) ----
        rdA(As[0], 0, aLo); rdB(Bs[0], 0, bLo);
        stageB(1, k1, 0);
        PH_SYNC_RD(); MFMA_Q(aLo, bLo, 0, 0); PH_END();
        // ---- phase 2: (1,0) ----
        rdA(As[0], 1, aHi); rdB(Bs[0], 1, bHi);
        stageB(1, k1, 1);
        PH_SYNC_RD(); MFMA_Q(aHi, bLo, 4, 0); PH_END();
        // ---- phase 3: (0,1) ---- (buf0 fully read; stage t+2 into it)
        if (!last) stageA(0, k2, 0);
        PH_SYNC(); MFMA_Q(aLo, bHi, 0, 2); PH_END();
        // ---- phase 4: (1,1) + gate tile t+1 ----
        if (!last) stageA(0, k2, 1);
        if (last) { asm volatile("s_waitcnt vmcnt(0)" ::: "memory"); }
        else      { asm volatile("s_waitcnt vmcnt(4)" ::: "memory"); }
        PH_SYNC(); MFMA_Q(aHi, bHi, 4, 2); PH_END();

        // ---- phase 5: tile t+1 quadrant (0,0) ----
        rdA(As[1], 0, aLo); rdB(Bs[1], 0, bLo);
        if (!last) stageB(0, k2, 0);
        PH_SYNC_RD(); MFMA_Q(aLo, bLo, 0, 0); PH_END();
        // ---- phase 6: (1,0) ----
        rdA(As[1], 1, aHi); rdB(Bs[1], 1, bHi);
        if (!last) stageB(0, k2, 1);
        PH_SYNC_RD(); MFMA_Q(aHi, bLo, 4, 0); PH_END();
        // ---- phase 7: (0,1) ---- (buf1 fully read; stage t+3 into it)
        if (!last) stageA(1, k3, 0);
        PH_SYNC(); MFMA_Q(aLo, bHi, 0, 2); PH_END();
        // ---- phase 8: (1,1) + gate tile t+2 ----
        if (!last) {
            stageA(1, k3, 1);
            asm volatile("s_waitcnt vmcnt(4)" ::: "memory");
        }
        PH_SYNC(); MFMA_Q(aHi, bHi, 4, 2); PH_END();
    }

    // ---- epilogue: C/D layout col = lane&15, row = (lane>>4)*4 + reg ----
    const int r0 = m0 + wr * 128;
    const int c0 = n0 + wc * 64;
#pragma unroll
    for (int i = 0; i < 8; ++i) {
#pragma unroll
        for (int j = 0; j < 4; ++j) {
            const int col = c0 + j * 16 + m_;
            const float bs = bias[col];
            float sc = 0.f, sh = 0.f;
            if constexpr (EPI == 1) { sc = scale[col]; sh = shift[col]; }
#pragma unroll
            for (int r = 0; r < 4; ++r) {
                float v = acc[i][j][r] + bs;
                if constexpr (EPI == 1) v = v * sc + sh;
                if constexpr (EPI == 2) v = fmaxf(v, 0.f);
                const int rowo = r0 + i * 16 + kg * 4 + r;
                C[(size_t)rowo * N + col] = f2b(v);
            }
        }
    }
}

// ---------------- Head mixing: out[b,t,h,d] = sum_s V[b,s,h,d] * M[h,s,t] ----
__global__ __launch_bounds__(256)
void mix_heads(const uint16_t* __restrict__ V, const float* __restrict__ Mh,
               uint16_t* __restrict__ out)
{
    __shared__ float Ms[32][132];  // [s][t]
    __shared__ float Vs[32][68];   // [s][d]
    const int h = blockIdx.x, b = blockIdx.y;
    const int tid = threadIdx.x;
    const int tx = tid & 15, ty = tid >> 4;

    float acc[8][4] = {};

    const float* Mbase = Mh + (size_t)h * MSL_ * MSL_;
    const uint16_t* Vbase = V + (size_t)b * MSL_ * D_ + h * DH_;

    for (int s0 = 0; s0 < MSL_; s0 += 32) {
#pragma unroll
        for (int i = 0; i < 4; ++i) {
            const int idx = tid + i * 256;
            const int row = idx >> 5;
            const int c4  = (idx & 31) << 2;
            *(float4*)&Ms[row][c4] =
                *(const float4*)(Mbase + (size_t)(s0 + row) * MSL_ + c4);
        }
#pragma unroll
        for (int i = 0; i < 2; ++i) {
            const int idx = tid + i * 256;
            const int row = idx >> 4;
            const int c4  = (idx & 15) << 2;
            ushort4 v = *(const ushort4*)(Vbase + (size_t)(s0 + row) * D_ + c4);
            Vs[row][c4 + 0] = b2f(v.x); Vs[row][c4 + 1] = b2f(v.y);
            Vs[row][c4 + 2] = b2f(v.z); Vs[row][c4 + 3] = b2f(v.w);
        }
        __syncthreads();
#pragma unroll
        for (int s = 0; s < 32; ++s) {
            float m8[8], v4[4];
            *(float4*)&m8[0] = *(const float4*)&Ms[s][ty * 8];
            *(float4*)&m8[4] = *(const float4*)&Ms[s][ty * 8 + 4];
            *(float4*)&v4[0] = *(const float4*)&Vs[s][tx * 4];
#pragma unroll
            for (int i = 0; i < 8; ++i)
#pragma unroll
                for (int j = 0; j < 4; ++j)
                    acc[i][j] += m8[i] * v4[j];
        }
        __syncthreads();
    }

    uint16_t* obase = out + (size_t)b * MSL_ * D_ + h * DH_ + tx * 4;
#pragma unroll
    for (int i = 0; i < 8; ++i) {
        ushort4 o;
        o.x = f2b(acc[i][0]); o.y = f2b(acc[i][1]);
        o.z = f2b(acc[i][2]); o.w = f2b(acc[i][3]);
        *(ushort4*)(obase + (size_t)(ty * 8 + i) * D_) = o;
    }
}

// ---------------- Classifier ----------------
__global__ void cls_kernel(const uint16_t* __restrict__ H, const float* __restrict__ W,
                           const float* __restrict__ bias, float* __restrict__ out)
{
    const int b = blockIdx.x;
    const int lane = threadIdx.x;
    const uint16_t* row = H + (size_t)b * MSL_ * D_;
    float s0 = 0.f, s1 = 0.f;
    for (int d = lane; d < D_; d += 64) {
        const float xv = b2f(row[d]);
        s0 += xv * W[d];
        s1 += xv * W[D_ + d];
    }
#pragma unroll
    for (int off = 32; off > 0; off >>= 1) {
        s0 += __shfl_down(s0, off);
        s1 += __shfl_down(s1, off);
    }
    if (lane == 0) {
        out[b * 2 + 0] = s0 + bias[0];
        out[b * 2 + 1] = s1 + bias[1];
    }
}

extern "C" void kernel_launch(void* const* d_in, const int* in_sizes, int n_in,
                              void* d_out, int out_size, void* d_ws, size_t ws_size,
                              hipStream_t stream)
{
    const float* x     = (const float*)d_in[0];
    const float* M0    = (const float*)d_in[1];
    const float* M1    = (const float*)d_in[2];
    const float* Wv_w  = (const float*)d_in[3];
    const float* Wv_b  = (const float*)d_in[4];
    const float* d0_w  = (const float*)d_in[5];
    const float* d0_b  = (const float*)d_in[6];
    const float* lnw   = (const float*)d_in[7];
    const float* lnb   = (const float*)d_in[8];
    const float* ff0_w = (const float*)d_in[9];
    const float* ff0_b = (const float*)d_in[10];
    const float* ff1_w = (const float*)d_in[11];
    const float* ff1_b = (const float*)d_in[12];
    const float* lnffw = (const float*)d_in[13];
    const float* lnffb = (const float*)d_in[14];
    const float* Wv1_w = (const float*)d_in[15];
    const float* Wv1_b = (const float*)d_in[16];
    const float* d01_w = (const float*)d_in[17];
    const float* d01_b = (const float*)d_in[18];
    const float* lnw1  = (const float*)d_in[19];
    const float* lnb1  = (const float*)d_in[20];
    const float* ff01_w = (const float*)d_in[21];
    const float* ff01_b = (const float*)d_in[22];
    const float* ff11_w = (const float*)d_in[23];
    const float* ff11_b = (const float*)d_in[24];
    const float* lnffw1 = (const float*)d_in[25];
    const float* lnffb1 = (const float*)d_in[26];
    const float* cls_w  = (const float*)d_in[27];
    const float* cls_b  = (const float*)d_in[28];

    // ---- workspace layout (ushort elements) ----
    const size_t NB = (size_t)ROWS_ * D_;           // 12,582,912
    const size_t WTOT = 2ull * (2ull * D_ * D_ + 2ull * DI_ * D_);  // 11,796,480
    uint16_t* A0 = (uint16_t*)d_ws;
    uint16_t* A1 = A0 + NB;
    uint16_t* A2 = A1 + NB;
    uint16_t* wp = A2 + NB;
    uint16_t* bWv[2], *bD0[2], *bF0[2], *bF1[2];
    for (int blk = 0; blk < 2; ++blk) {
        bWv[blk] = wp; wp += (size_t)D_ * D_;
        bD0[blk] = wp; wp += (size_t)D_ * D_;
        bF0[blk] = wp; wp += (size_t)DI_ * D_;
        bF1[blk] = wp; wp += (size_t)D_ * DI_;
    }
    const size_t used_alias = (3ull * NB + WTOT) * sizeof(uint16_t);
    const size_t need_full  = used_alias + 4ull * NB * sizeof(uint16_t);
    const bool full = (ws_size >= need_full);
    uint16_t* F = full ? wp : A0;                   // FULL: dedicated; ALIAS: [A0;A1]
    const int CH = full ? ROWS_ : (ROWS_ / 2);      // 16384 or 8192 (both %256==0)

    auto cvt = [&](const float* in, uint16_t* out, size_t n) {
        const int n4 = (int)(n / 4);
        cvt_f32_bf16<<<dim3((n4 + 255) / 256), dim3(256), 0, stream>>>(in, out, n4);
    };

    cvt(x, A2, NB);
    cvt(Wv_w,  bWv[0], (size_t)D_ * D_);
    cvt(d0_w,  bD0[0], (size_t)D_ * D_);
    cvt(ff0_w, bF0[0], (size_t)DI_ * D_);
    cvt(ff1_w, bF1[0], (size_t)D_ * DI_);
    cvt(Wv1_w, bWv[1], (size_t)D_ * D_);
    cvt(d01_w, bD0[1], (size_t)D_ * D_);
    cvt(ff01_w, bF0[1], (size_t)DI_ * D_);
    cvt(ff11_w, bF1[1], (size_t)D_ * DI_);

    const dim3 blk256(256);
    const dim3 blk512(512);

    auto gemm = [&](int EPI, const uint16_t* Ain, const uint16_t* Bw,
                    const float* bias, const float* sc, const float* sh,
                    uint16_t* Cout, int M, int N, int K) {
        const int gx = N / 256;
        const dim3 grid(gx * (M / 256));
        if (EPI == 0)
            gemm_bf16<0><<<grid, blk512, 0, stream>>>(Ain, Bw, bias, sc, sh, Cout, M, N, K, gx);
        else if (EPI == 1)
            gemm_bf16<1><<<grid, blk512, 0, stream>>>(Ain, Bw, bias, sc, sh, Cout, M, N, K, gx);
        else
            gemm_bf16<2><<<grid, blk512, 0, stream>>>(Ain, Bw, bias, sc, sh, Cout, M, N, K, gx);
    };

    // Per transformer block (input & output = A2):
    //   V: A2->A0 ; mix: A0->A1 ; dense0: A1->A2 ; FFN chunks on A2 (A0,A1 dead).
    auto run_block = [&](const float* Mm, int bi,
                         const float* wv_b, const float* db,
                         const float* lw, const float* lb,
                         const float* f0b, const float* f1b,
                         const float* lfw, const float* lfb) {
        gemm(0, A2, bWv[bi], wv_b, nullptr, nullptr, A0, ROWS_, D_, D_);
        mix_heads<<<dim3(NH_, BS_), blk256, 0, stream>>>(A0, Mm, A1);
        gemm(1, A1, bD0[bi], db, lw, lb, A2, ROWS_, D_, D_);
        for (int c = 0; c < ROWS_; c += CH) {
            gemm(2, A2 + (size_t)c * D_, bF0[bi], f0b, nullptr, nullptr, F, CH, DI_, D_);
            gemm(1, F, bF1[bi], f1b, lfw, lfb, A2 + (size_t)c * D_, CH, D_, DI_);
        }
    };

    run_block(M0, 0, Wv_b, d0_b, lnw, lnb, ff0_b, ff1_b, lnffw, lnffb);
    run_block(M1, 1, Wv1_b, d01_b, lnw1, lnb1, ff01_b, ff11_b, lnffw1, lnffb1);

    cls_kernel<<<dim3(BS_), dim3(64), 0, stream>>>(A2, cls_w, cls_b, (float*)d_out);
}

// Round 8
// 567.065 us; speedup vs baseline: 1.2699x; 1.2699x over previous
//
#include <hip/hip_runtime.h>
#include <cstdint>
#include <cstddef>

#define BS_   128
#define MSL_  128
#define D_    768
#define NH_   12
#define DH_   64
#define DI_   3072
#define ROWS_ (BS_ * MSL_)   // 16384
#define MT_SZ (NH_ * MSL_ * MSL_)   // 196608 elements per M matrix

using bf16x8 = __attribute__((ext_vector_type(8))) __bf16;
using f32x4  = __attribute__((ext_vector_type(4))) float;

// Exact RNE f32 -> bf16 bits.
static __device__ __forceinline__ uint16_t f2b(float f) {
    uint32_t u = __builtin_bit_cast(uint32_t, f);
    u += 0x7fffu + ((u >> 16) & 1u);
    return (uint16_t)(u >> 16);
}
static __device__ __forceinline__ float b2f(uint16_t h) {
    uint32_t u = ((uint32_t)h) << 16;
    return __builtin_bit_cast(float, u);
}

__global__ __launch_bounds__(256)
void cvt_f32_bf16(const float* __restrict__ in, uint16_t* __restrict__ out, int n4) {
    int i = blockIdx.x * blockDim.x + threadIdx.x;
    if (i >= n4) return;
    float4 v = ((const float4*)in)[i];
    ushort4 o;
    o.x = f2b(v.x); o.y = f2b(v.y); o.z = f2b(v.z); o.w = f2b(v.w);
    ((ushort4*)out)[i] = o;
}

// async global->LDS, 16B per lane. LDS dest is wave-uniform base (+lane*16 in HW).
static __device__ __forceinline__ void gload16(const uint16_t* g, uint16_t* l) {
    __builtin_amdgcn_global_load_lds(
        (__attribute__((address_space(1))) void*)(uintptr_t)g,
        (__attribute__((address_space(3))) void*)(uintptr_t)l,
        16, 0, 0);
}

// ---------------- bf16 MFMA GEMM: C = epi(A @ B^T + bias) ----------------
// A: [M][K] bf16 row-major, B: [N][K] bf16 row-major, C: [M][N] bf16.
// EPI: 0 = +bias; 1 = (+bias)*scale+shift; 2 = relu(+bias)
// TRANSV: epilogue writes head-transposed Vt[b][h][d][s] (V-GEMM only).
// 256x256 tile, BK=64, 8 waves (2Mx4N), per-wave 128x64 output.
// Counted-vmcnt 2-phase (round-6 proven): B1 (WAR) -> stage(t+1 -> buf^1)
// -> vmcnt(8) (own tile-t landed) -> B2 (RAW) -> compute tile t.
// LDS chunk swizzle: phys16Bchunk = logical ^ (row&7), on BOTH the global
// source and the ds_read (involution, rule #21) -> conflict-free (0 measured).
template<int EPI, int TRANSV>
__global__ __launch_bounds__(512, 2)
void gemm_bf16(const uint16_t* __restrict__ A, const uint16_t* __restrict__ B,
               const float* __restrict__ bias, const float* __restrict__ scale,
               const float* __restrict__ shift, uint16_t* __restrict__ C,
               int M, int N, int K, int gx)
{
    __shared__ __align__(16) uint16_t As[2][256 * 64];
    __shared__ __align__(16) uint16_t Bs[2][256 * 64];
    const int tid  = threadIdx.x;
    const int lane = tid & 63;
    const int m_   = lane & 15;
    const int kg   = lane >> 4;           // k-group 0..3 (8 bf16 each)
    const int w    = tid >> 6;
    const int wr   = w >> 2;              // 0..1
    const int wc   = w & 3;               // 0..3

    // T1 bijective XCD swizzle (nwg % 8 == 0 for all grids used here).
    const int nwg = gridDim.x;
    const int q   = nwg >> 3;
    const int wg  = (blockIdx.x & 7) * q + (blockIdx.x >> 3);
    const int m0  = (wg / gx) * 256;
    const int n0  = (wg % gx) * 256;

    f32x4 acc[8][4] = {};

    // Staging: tile = 256 rows x 64 bf16 = 2048 16B-chunks per matrix;
    // 512 threads x 4 chunks. Chunk c holds (row=c>>3, logical slot (c&7)^(row&7)).
    int srow[4], ssl[4], sbase[4];
#pragma unroll
    for (int it = 0; it < 4; ++it) {
        const int c = it * 512 + tid;
        srow[it]  = c >> 3;
        ssl[it]   = (c & 7) ^ (srow[it] & 7);
        sbase[it] = (it * 512 + (tid & 448)) * 8;   // wave-uniform 16B-chunk base
    }
    auto stage = [&](int buf, int k0) {
#pragma unroll
        for (int it = 0; it < 4; ++it)
            gload16(A + (size_t)(m0 + srow[it]) * K + k0 + ssl[it] * 8,
                    &As[buf][sbase[it]]);
#pragma unroll
        for (int it = 0; it < 4; ++it)
            gload16(B + (size_t)(n0 + srow[it]) * K + k0 + ssl[it] * 8,
                    &Bs[buf][sbase[it]]);
    };

    stage(0, 0);
    const int NT = K >> 6;
    for (int t = 0; t < NT; ++t) {
        const int buf = t & 1;
        __builtin_amdgcn_s_barrier();          // B1: buf^1 free (prev readers done)
        __builtin_amdgcn_sched_barrier(0);
        if (t + 1 < NT) {
            stage(buf ^ 1, (t + 1) << 6);
            asm volatile("s_waitcnt vmcnt(8)" ::: "memory");  // own tile-t landed
        } else {
            asm volatile("s_waitcnt vmcnt(0)" ::: "memory");
        }
        __builtin_amdgcn_s_barrier();          // B2: tile t visible to ALL waves
        __builtin_amdgcn_sched_barrier(0);

        // A fragments for this wave: rows wr*128 + i*16 + m_, full K=64.
        bf16x8 a[8][2];
#pragma unroll
        for (int i = 0; i < 8; ++i) {
            const int row = wr * 128 + i * 16 + m_;
#pragma unroll
            for (int kk = 0; kk < 2; ++kk) {
                const int ch = (kk * 4 + kg) ^ (m_ & 7);
                a[i][kk] = *reinterpret_cast<const bf16x8*>(
                    &As[buf][row * 64 + ch * 8]);
            }
        }
        // 4 phases over B column-fragments; setprio around each MFMA cluster.
#pragma unroll
        for (int j = 0; j < 4; ++j) {
            const int row = wc * 64 + j * 16 + m_;
            const bf16x8 b0 = *reinterpret_cast<const bf16x8*>(
                &Bs[buf][row * 64 + ((0 + kg) ^ (m_ & 7)) * 8]);
            const bf16x8 b1 = *reinterpret_cast<const bf16x8*>(
                &Bs[buf][row * 64 + ((4 + kg) ^ (m_ & 7)) * 8]);
            __builtin_amdgcn_s_setprio(1);
#pragma unroll
            for (int i = 0; i < 8; ++i) {
                acc[i][j] = __builtin_amdgcn_mfma_f32_16x16x32_bf16(
                    a[i][0], b0, acc[i][j], 0, 0, 0);
                acc[i][j] = __builtin_amdgcn_mfma_f32_16x16x32_bf16(
                    a[i][1], b1, acc[i][j], 0, 0, 0);
            }
            __builtin_amdgcn_s_setprio(0);
        }
    }

    // ---- epilogue: C/D layout col = lane&15, row = (lane>>4)*4 + reg ----
    const int r0 = m0 + wr * 128;
    const int c0 = n0 + wc * 64;
#pragma unroll
    for (int i = 0; i < 8; ++i) {
#pragma unroll
        for (int j = 0; j < 4; ++j) {
            const int col = c0 + j * 16 + m_;
            const float bs = bias[col];
            float sc = 0.f, sh = 0.f;
            if constexpr (EPI == 1) { sc = scale[col]; sh = shift[col]; }
            if constexpr (TRANSV) {
                // Vt[b][h][d][s]: 4 consecutive s per lane -> ushort4 store.
                const int rowb = r0 + i * 16 + kg * 4;
                const int bb = rowb >> 7, s0 = rowb & 127;
                const int hh = col >> 6,  dd = col & 63;
                ushort4 o;
#pragma unroll
                for (int r = 0; r < 4; ++r) {
                    float v = acc[i][j][r] + bs;
                    (&o.x)[r] = f2b(v);
                }
                *(ushort4*)(C + (((size_t)bb * NH_ + hh) * DH_ + dd) * MSL_ + s0) = o;
            } else {
#pragma unroll
                for (int r = 0; r < 4; ++r) {
                    float v = acc[i][j][r] + bs;
                    if constexpr (EPI == 1) v = v * sc + sh;
                    if constexpr (EPI == 2) v = fmaxf(v, 0.f);
                    const int rowo = r0 + i * 16 + kg * 4 + r;
                    C[(size_t)rowo * N + col] = f2b(v);
                }
            }
        }
    }
}

// ---------------- M transpose: MhT[h][t][s] (bf16) = M[h][s][t] (f32) --------
__global__ __launch_bounds__(256)
void mtrans(const float* __restrict__ M, uint16_t* __restrict__ MT)
{
    __shared__ float tile[32][33];
    const int h  = blockIdx.x;
    const int ti = blockIdx.y & 3, si = blockIdx.y >> 2;
    const int tx = threadIdx.x & 31, ty = threadIdx.x >> 5;  // 32x8
    const float* src = M + (size_t)h * MSL_ * MSL_;
    uint16_t*    dst = MT + (size_t)h * MSL_ * MSL_;
#pragma unroll
    for (int k = 0; k < 4; ++k)
        tile[ty + 8 * k][tx] = src[(size_t)(si * 32 + ty + 8 * k) * MSL_ + ti * 32 + tx];
    __syncthreads();
#pragma unroll
    for (int k = 0; k < 4; ++k)
        dst[(size_t)(ti * 32 + ty + 8 * k) * MSL_ + si * 32 + tx] = f2b(tile[tx][ty + 8 * k]);
}

// ---------------- Head mixing (MFMA): out[b,t,h,d] = sum_s MhT[h,t,s]*Vt[b,h,d,s]
// Block per (h, b); 4 waves, each 32 t-rows x 64 d-cols. Operands straight from
// global (both contiguous bf16x8 by construction); no LDS.
__global__ __launch_bounds__(256)
void mix_mfma(const uint16_t* __restrict__ MhT, const uint16_t* __restrict__ Vt,
              uint16_t* __restrict__ out)
{
    const int h = blockIdx.x, b = blockIdx.y;
    const int tid  = threadIdx.x;
    const int lane = tid & 63;
    const int m_   = lane & 15;
    const int kg   = lane >> 4;
    const int w    = tid >> 6;          // 0..3 -> t-rows w*32..w*32+31

    const uint16_t* Abase = MhT + (size_t)h * MSL_ * MSL_;
    const uint16_t* Bbase = Vt + ((size_t)b * NH_ + h) * DH_ * MSL_;

    f32x4 acc[2][4] = {};
#pragma unroll
    for (int k0 = 0; k0 < MSL_; k0 += 32) {
        bf16x8 a[2], bf[4];
#pragma unroll
        for (int i = 0; i < 2; ++i)
            a[i] = *reinterpret_cast<const bf16x8*>(
                &Abase[(size_t)(w * 32 + i * 16 + m_) * MSL_ + k0 + kg * 8]);
#pragma unroll
        for (int j = 0; j < 4; ++j)
            bf[j] = *reinterpret_cast<const bf16x8*>(
                &Bbase[(size_t)(j * 16 + m_) * MSL_ + k0 + kg * 8]);
#pragma unroll
        for (int i = 0; i < 2; ++i)
#pragma unroll
            for (int j = 0; j < 4; ++j)
                acc[i][j] = __builtin_amdgcn_mfma_f32_16x16x32_bf16(
                    a[i], bf[j], acc[i][j], 0, 0, 0);
    }

    // out standard layout: row = b*128 + t, col = h*64 + d
#pragma unroll
    for (int i = 0; i < 2; ++i) {
#pragma unroll
        for (int j = 0; j < 4; ++j) {
            const int t0 = w * 32 + i * 16 + kg * 4;
            const int dd = j * 16 + m_;
#pragma unroll
            for (int r = 0; r < 4; ++r)
                out[(size_t)(b * MSL_ + t0 + r) * D_ + h * DH_ + dd] =
                    f2b(acc[i][j][r]);
        }
    }
}

// ---------------- Classifier ----------------
__global__ void cls_kernel(const uint16_t* __restrict__ H, const float* __restrict__ W,
                           const float* __restrict__ bias, float* __restrict__ out)
{
    const int b = blockIdx.x;
    const int lane = threadIdx.x;
    const uint16_t* row = H + (size_t)b * MSL_ * D_;
    float s0 = 0.f, s1 = 0.f;
    for (int d = lane; d < D_; d += 64) {
        const float xv = b2f(row[d]);
        s0 += xv * W[d];
        s1 += xv * W[D_ + d];
    }
#pragma unroll
    for (int off = 32; off > 0; off >>= 1) {
        s0 += __shfl_down(s0, off);
        s1 += __shfl_down(s1, off);
    }
    if (lane == 0) {
        out[b * 2 + 0] = s0 + bias[0];
        out[b * 2 + 1] = s1 + bias[1];
    }
}

extern "C" void kernel_launch(void* const* d_in, const int* in_sizes, int n_in,
                              void* d_out, int out_size, void* d_ws, size_t ws_size,
                              hipStream_t stream)
{
    const float* x     = (const float*)d_in[0];
    const float* M0    = (const float*)d_in[1];
    const float* M1    = (const float*)d_in[2];
    const float* Wv_w  = (const float*)d_in[3];
    const float* Wv_b  = (const float*)d_in[4];
    const float* d0_w  = (const float*)d_in[5];
    const float* d0_b  = (const float*)d_in[6];
    const float* lnw   = (const float*)d_in[7];
    const float* lnb   = (const float*)d_in[8];
    const float* ff0_w = (const float*)d_in[9];
    const float* ff0_b = (const float*)d_in[10];
    const float* ff1_w = (const float*)d_in[11];
    const float* ff1_b = (const float*)d_in[12];
    const float* lnffw = (const float*)d_in[13];
    const float* lnffb = (const float*)d_in[14];
    const float* Wv1_w = (const float*)d_in[15];
    const float* Wv1_b = (const float*)d_in[16];
    const float* d01_w = (const float*)d_in[17];
    const float* d01_b = (const float*)d_in[18];
    const float* lnw1  = (const float*)d_in[19];
    const float* lnb1  = (const float*)d_in[20];
    const float* ff01_w = (const float*)d_in[21];
    const float* ff01_b = (const float*)d_in[22];
    const float* ff11_w = (const float*)d_in[23];
    const float* ff11_b = (const float*)d_in[24];
    const float* lnffw1 = (const float*)d_in[25];
    const float* lnffb1 = (const float*)d_in[26];
    const float* cls_w  = (const float*)d_in[27];
    const float* cls_b  = (const float*)d_in[28];

    // ---- workspace layout (ushort elements) ----
    const size_t NB = (size_t)ROWS_ * D_;           // 12,582,912
    const size_t WTOT = 2ull * (2ull * D_ * D_ + 2ull * DI_ * D_);  // 11,796,480
    uint16_t* A0 = (uint16_t*)d_ws;
    uint16_t* A1 = A0 + NB;
    uint16_t* A2 = A1 + NB;
    uint16_t* wp = A2 + NB;
    uint16_t* bWv[2], *bD0[2], *bF0[2], *bF1[2];
    for (int blk = 0; blk < 2; ++blk) {
        bWv[blk] = wp; wp += (size_t)D_ * D_;
        bD0[blk] = wp; wp += (size_t)D_ * D_;
        bF0[blk] = wp; wp += (size_t)DI_ * D_;
        bF1[blk] = wp; wp += (size_t)D_ * DI_;
    }
    const size_t used_alias = (3ull * NB + WTOT) * sizeof(uint16_t);
    // FULL needs F (4*NB) + MhT (2*MT_SZ) after the weights.
    const size_t need_full  = used_alias + (4ull * NB + 2ull * MT_SZ) * sizeof(uint16_t);
    const bool full = (ws_size >= need_full);
    uint16_t* F  = full ? wp : A0;                  // FULL: dedicated; ALIAS: [A0;A1]
    uint16_t* mt = full ? (wp + 4ull * NB) : wp;    // MhT[2][12][128][128]
    const int CH = full ? ROWS_ : (ROWS_ / 2);      // 16384 or 8192 (both %256==0)

    auto cvt = [&](const float* in, uint16_t* out, size_t n) {
        const int n4 = (int)(n / 4);
        cvt_f32_bf16<<<dim3((n4 + 255) / 256), dim3(256), 0, stream>>>(in, out, n4);
    };

    cvt(x, A2, NB);
    cvt(Wv_w,  bWv[0], (size_t)D_ * D_);
    cvt(d0_w,  bD0[0], (size_t)D_ * D_);
    cvt(ff0_w, bF0[0], (size_t)DI_ * D_);
    cvt(ff1_w, bF1[0], (size_t)D_ * DI_);
    cvt(Wv1_w, bWv[1], (size_t)D_ * D_);
    cvt(d01_w, bD0[1], (size_t)D_ * D_);
    cvt(ff01_w, bF0[1], (size_t)DI_ * D_);
    cvt(ff11_w, bF1[1], (size_t)D_ * DI_);
    mtrans<<<dim3(NH_, 16), dim3(256), 0, stream>>>(M0, mt);
    mtrans<<<dim3(NH_, 16), dim3(256), 0, stream>>>(M1, mt + MT_SZ);

    const dim3 blk256(256);
    const dim3 blk512(512);

    auto gemm = [&](int EPI, const uint16_t* Ain, const uint16_t* Bw,
                    const float* bias, const float* sc, const float* sh,
                    uint16_t* Cout, int M, int N, int K) {
        const int gx = N / 256;
        const dim3 grid(gx * (M / 256));
        if (EPI == 0)
            gemm_bf16<0, 0><<<grid, blk512, 0, stream>>>(Ain, Bw, bias, sc, sh, Cout, M, N, K, gx);
        else if (EPI == 1)
            gemm_bf16<1, 0><<<grid, blk512, 0, stream>>>(Ain, Bw, bias, sc, sh, Cout, M, N, K, gx);
        else
            gemm_bf16<2, 0><<<grid, blk512, 0, stream>>>(Ain, Bw, bias, sc, sh, Cout, M, N, K, gx);
    };

    // Per transformer block (input & output = A2):
    //   V(TRANSV): A2 -> A0 (Vt layout) ; mix_mfma: A0 -> A1 (standard) ;
    //   dense0: A1 -> A2 ; FFN chunks on A2 (A0, A1 dead).
    auto run_block = [&](int bi,
                         const float* wv_b, const float* db,
                         const float* lw, const float* lb,
                         const float* f0b, const float* f1b,
                         const float* lfw, const float* lfb) {
        gemm_bf16<0, 1><<<dim3((D_ / 256) * (ROWS_ / 256)), blk512, 0, stream>>>(
            A2, bWv[bi], wv_b, nullptr, nullptr, A0, ROWS_, D_, D_, D_ / 256);
        mix_mfma<<<dim3(NH_, BS_), blk256, 0, stream>>>(mt + (size_t)bi * MT_SZ, A0, A1);
        gemm(1, A1, bD0[bi], db, lw, lb, A2, ROWS_, D_, D_);
        for (int c = 0; c < ROWS_; c += CH) {
            gemm(2, A2 + (size_t)c * D_, bF0[bi], f0b, nullptr, nullptr, F, CH, DI_, D_);
            gemm(1, F, bF1[bi], f1b, lfw, lfb, A2 + (size_t)c * D_, CH, D_, DI_);
        }
    };

    run_block(0, Wv_b, d0_b, lnw, lnb, ff0_b, ff1_b, lnffw, lnffb);
    run_block(1, Wv1_b, d01_b, lnw1, lnb1, ff01_b, ff11_b, lnffw1, lnffb1);

    cls_kernel<<<dim3(BS_), dim3(64), 0, stream>>>(A2, cls_w, cls_b, (float*)d_out);
}

// Round 9
// 534.440 us; speedup vs baseline: 1.3474x; 1.0610x over previous
//
#include <hip/hip_runtime.h>
#include <cstdint>
#include <cstddef>

#define BS_   128
#define MSL_  128
#define D_    768
#define NH_   12
#define DH_   64
#define DI_   3072
#define ROWS_ (BS_ * MSL_)   // 16384
#define MT_SZ (NH_ * MSL_ * MSL_)   // 196608 elements per M matrix

using bf16x8 = __attribute__((ext_vector_type(8))) __bf16;
using f32x4  = __attribute__((ext_vector_type(4))) float;

// Exact RNE f32 -> bf16 bits.
static __device__ __forceinline__ uint16_t f2b(float f) {
    uint32_t u = __builtin_bit_cast(uint32_t, f);
    u += 0x7fffu + ((u >> 16) & 1u);
    return (uint16_t)(u >> 16);
}
static __device__ __forceinline__ float b2f(uint16_t h) {
    uint32_t u = ((uint32_t)h) << 16;
    return __builtin_bit_cast(float, u);
}

__global__ __launch_bounds__(256)
void cvt_f32_bf16(const float* __restrict__ in, uint16_t* __restrict__ out, int n4) {
    int i = blockIdx.x * blockDim.x + threadIdx.x;
    if (i >= n4) return;
    float4 v = ((const float4*)in)[i];
    ushort4 o;
    o.x = f2b(v.x); o.y = f2b(v.y); o.z = f2b(v.z); o.w = f2b(v.w);
    ((ushort4*)out)[i] = o;
}

// async global->LDS, 16B per lane. LDS dest is wave-uniform base (+lane*16 in HW).
static __device__ __forceinline__ void gload16(const uint16_t* g, uint16_t* l) {
    __builtin_amdgcn_global_load_lds(
        (__attribute__((address_space(1))) void*)(uintptr_t)g,
        (__attribute__((address_space(3))) void*)(uintptr_t)l,
        16, 0, 0);
}

// ---------------- bf16 MFMA GEMM: C = epi(A @ B^T + bias) ----------------
// A: [M][K] bf16 row-major, B: [N][K] bf16 row-major, C: [M][N] bf16.
// EPI: 0 = +bias; 1 = (+bias)*scale+shift; 2 = relu(+bias)
// TRANSV: epilogue writes head-transposed Vt[b][h][d][s] (V-GEMM only).
// 256x256 tile, BK=64, 8 waves (2Mx4N), per-wave 128x64 output.
// 8-phase counted-vmcnt schedule (m201 template, de-pinned):
//   per phase: {just-in-time ds_reads (12/8/4/0); stage 1 half-tile (2 gloads);
//   [vmcnt gate at p4/p8 only]; BAR; lgkmcnt(0); setprio(1) 16 MFMA setprio(0);
//   BAR}.  NO sched_barrier(0) (m141: order-pinning regresses; ds_reads are
//   compiler-visible so data deps are tracked).  vmcnt never drains to 0 in
//   the main loop; stage lead = 1 K-tile (B halves at p1/p2, A at p3/p4 etc).
// LDS chunk swizzle: phys16Bchunk = logical ^ (row&7), on BOTH the global
// source and the ds_read (involution, rule #21) -> conflict-free (0 measured).
// M % 256 == 0, N % 256 == 0, K % 128 == 0 (K/64 even: K in {768, 3072}).
template<int EPI, int TRANSV>
__global__ __launch_bounds__(512, 2)
void gemm_bf16(const uint16_t* __restrict__ A, const uint16_t* __restrict__ B,
               const float* __restrict__ bias, const float* __restrict__ scale,
               const float* __restrict__ shift, uint16_t* __restrict__ C,
               int M, int N, int K, int gx)
{
    __shared__ __align__(16) uint16_t As[2][256 * 64];
    __shared__ __align__(16) uint16_t Bs[2][256 * 64];
    const int tid  = threadIdx.x;
    const int lane = tid & 63;
    const int m_   = lane & 15;
    const int kg   = lane >> 4;           // k-group 0..3 (8 bf16 each)
    const int w    = tid >> 6;
    const int wr   = w >> 2;              // 0..1
    const int wc   = w & 3;               // 0..3

    // T1 bijective XCD swizzle (nwg % 8 == 0 for all grids used here).
    const int nwg = gridDim.x;
    const int q   = nwg >> 3;
    const int wg  = (blockIdx.x & 7) * q + (blockIdx.x >> 3);
    const int m0  = (wg / gx) * 256;
    const int n0  = (wg % gx) * 256;

    f32x4 acc[8][4] = {};

    // Staging map: tile = 256 rows x 8 chunks(16B); 4 chunks/thread.
    // it 0,1 -> rows 0..127 (half 0); it 2,3 -> rows 128..255 (half 1).
    int srow[4], ssl[4], sbase[4];
#pragma unroll
    for (int it = 0; it < 4; ++it) {
        const int c = it * 512 + tid;
        srow[it]  = c >> 3;
        ssl[it]   = (c & 7) ^ (srow[it] & 7);
        sbase[it] = (it * 512 + (tid & 448)) * 8;   // wave-uniform chunk base
    }
    auto stageA = [&](int buf, int k0, int half) {
        const int it0 = half * 2, it1 = it0 + 1;
        gload16(A + (size_t)(m0 + srow[it0]) * K + k0 + ssl[it0] * 8, &As[buf][sbase[it0]]);
        gload16(A + (size_t)(m0 + srow[it1]) * K + k0 + ssl[it1] * 8, &As[buf][sbase[it1]]);
    };
    auto stageB = [&](int buf, int k0, int half) {
        const int it0 = half * 2, it1 = it0 + 1;
        gload16(B + (size_t)(n0 + srow[it0]) * K + k0 + ssl[it0] * 8, &Bs[buf][sbase[it0]]);
        gload16(B + (size_t)(n0 + srow[it1]) * K + k0 + ssl[it1] * 8, &Bs[buf][sbase[it1]]);
    };

    auto rdAh = [&](const uint16_t* S, int half, bf16x8 (&dst)[4][2]) {
#pragma unroll
        for (int i = 0; i < 4; ++i) {
            const int row = wr * 128 + half * 64 + i * 16 + m_;
#pragma unroll
            for (int kk = 0; kk < 2; ++kk)
                dst[i][kk] = *reinterpret_cast<const bf16x8*>(
                    &S[row * 64 + (((kk * 4 + kg) ^ (m_ & 7)) * 8)]);
        }
    };
    auto rdBp = [&](const uint16_t* S, int jp, bf16x8 (&dst)[2][2]) {
#pragma unroll
        for (int j = 0; j < 2; ++j) {
            const int row = wc * 64 + (jp * 2 + j) * 16 + m_;
#pragma unroll
            for (int kk = 0; kk < 2; ++kk)
                dst[j][kk] = *reinterpret_cast<const bf16x8*>(
                    &S[row * 64 + (((kk * 4 + kg) ^ (m_ & 7)) * 8)]);
        }
    };
    auto mfmaQ = [&](bf16x8 (&A4)[4][2], bf16x8 (&B2)[2][2], int io, int jo) {
        __builtin_amdgcn_s_setprio(1);
#pragma unroll
        for (int i = 0; i < 4; ++i)
#pragma unroll
            for (int j = 0; j < 2; ++j) {
                acc[io + i][jo + j] = __builtin_amdgcn_mfma_f32_16x16x32_bf16(
                    A4[i][0], B2[j][0], acc[io + i][jo + j], 0, 0, 0);
                acc[io + i][jo + j] = __builtin_amdgcn_mfma_f32_16x16x32_bf16(
                    A4[i][1], B2[j][1], acc[io + i][jo + j], 0, 0, 0);
            }
        __builtin_amdgcn_s_setprio(0);
    };

#define BAR()  __builtin_amdgcn_s_barrier()
#define LGKM() asm volatile("s_waitcnt lgkmcnt(0)" ::: "memory")

    // ---- prologue: tile0 full + tile1 A-halves; gate tile0 ----
    stageA(0, 0, 0); stageA(0, 0, 1); stageB(0, 0, 0); stageB(0, 0, 1);
    stageA(1, 64, 0); stageA(1, 64, 1);
    asm volatile("s_waitcnt vmcnt(4)" ::: "memory");   // tile0's 8 loads landed
    BAR();

    bf16x8 aLo[4][2], aHi[4][2], bLo[2][2], bHi[2][2];
    const int NT = K >> 6;   // even
    for (int t = 0; t < NT; t += 2) {
        const bool last = (t + 2 >= NT);
        const int k1 = (t + 1) << 6, k2 = (t + 2) << 6, k3 = (t + 3) << 6;

        // p1: tile t quadrant (lo,lo)
        rdAh(As[0], 0, aLo); rdBp(Bs[0], 0, bLo);
        stageB(1, k1, 0);
        BAR(); LGKM(); mfmaQ(aLo, bLo, 0, 0); BAR();
        // p2: (hi,lo)
        rdAh(As[0], 1, aHi);
        stageB(1, k1, 1);
        BAR(); LGKM(); mfmaQ(aHi, bLo, 4, 0); BAR();
        // p3: (lo,hi)  (buf0 A fully read -> stage t+2 A into it)
        rdBp(Bs[0], 1, bHi);
        if (!last) stageA(0, k2, 0);
        BAR(); LGKM(); mfmaQ(aLo, bHi, 0, 2); BAR();
        // p4: (hi,hi) + gate tile t+1
        if (!last) { stageA(0, k2, 1);
                     asm volatile("s_waitcnt vmcnt(4)" ::: "memory"); }
        else       { asm volatile("s_waitcnt vmcnt(0)" ::: "memory"); }
        BAR(); mfmaQ(aHi, bHi, 4, 2); BAR();

        // p5: tile t+1 quadrant (lo,lo)
        rdAh(As[1], 0, aLo); rdBp(Bs[1], 0, bLo);
        if (!last) stageB(0, k2, 0);
        BAR(); LGKM(); mfmaQ(aLo, bLo, 0, 0); BAR();
        // p6: (hi,lo)
        rdAh(As[1], 1, aHi);
        if (!last) stageB(0, k2, 1);
        BAR(); LGKM(); mfmaQ(aHi, bLo, 4, 0); BAR();
        // p7: (lo,hi)
        rdBp(Bs[1], 1, bHi);
        if (!last) stageA(1, k3, 0);
        BAR(); LGKM(); mfmaQ(aLo, bHi, 0, 2); BAR();
        // p8: (hi,hi) + gate tile t+2
        if (!last) { stageA(1, k3, 1);
                     asm volatile("s_waitcnt vmcnt(4)" ::: "memory"); }
        BAR(); mfmaQ(aHi, bHi, 4, 2); BAR();
    }
#undef BAR
#undef LGKM

    // ---- epilogue: C/D layout col = lane&15, row = (lane>>4)*4 + reg ----
    const int r0 = m0 + wr * 128;
    const int c0 = n0 + wc * 64;
#pragma unroll
    for (int i = 0; i < 8; ++i) {
#pragma unroll
        for (int j = 0; j < 4; ++j) {
            const int col = c0 + j * 16 + m_;
            const float bs = bias[col];
            float sc = 0.f, sh = 0.f;
            if constexpr (EPI == 1) { sc = scale[col]; sh = shift[col]; }
            if constexpr (TRANSV) {
                // Vt[b][h][d][s]: 4 consecutive s per lane -> ushort4 store.
                const int rowb = r0 + i * 16 + kg * 4;
                const int bb = rowb >> 7, s0 = rowb & 127;
                const int hh = col >> 6,  dd = col & 63;
                ushort4 o;
#pragma unroll
                for (int r = 0; r < 4; ++r) {
                    float v = acc[i][j][r] + bs;
                    (&o.x)[r] = f2b(v);
                }
                *(ushort4*)(C + (((size_t)bb * NH_ + hh) * DH_ + dd) * MSL_ + s0) = o;
            } else {
#pragma unroll
                for (int r = 0; r < 4; ++r) {
                    float v = acc[i][j][r] + bs;
                    if constexpr (EPI == 1) v = v * sc + sh;
                    if constexpr (EPI == 2) v = fmaxf(v, 0.f);
                    const int rowo = r0 + i * 16 + kg * 4 + r;
                    C[(size_t)rowo * N + col] = f2b(v);
                }
            }
        }
    }
}

// ---------------- M transpose: MhT[h][t][s] (bf16) = M[h][s][t] (f32) --------
__global__ __launch_bounds__(256)
void mtrans(const float* __restrict__ M, uint16_t* __restrict__ MT)
{
    __shared__ float tile[32][33];
    const int h  = blockIdx.x;
    const int ti = blockIdx.y & 3, si = blockIdx.y >> 2;
    const int tx = threadIdx.x & 31, ty = threadIdx.x >> 5;  // 32x8
    const float* src = M + (size_t)h * MSL_ * MSL_;
    uint16_t*    dst = MT + (size_t)h * MSL_ * MSL_;
#pragma unroll
    for (int k = 0; k < 4; ++k)
        tile[ty + 8 * k][tx] = src[(size_t)(si * 32 + ty + 8 * k) * MSL_ + ti * 32 + tx];
    __syncthreads();
#pragma unroll
    for (int k = 0; k < 4; ++k)
        dst[(size_t)(ti * 32 + ty + 8 * k) * MSL_ + si * 32 + tx] = f2b(tile[tx][ty + 8 * k]);
}

// ---------------- Head mixing (MFMA): out[b,t,h,d] = sum_s MhT[h,t,s]*Vt[b,h,d,s]
// Block per (h, b); 4 waves, each 32 t-rows x 64 d-cols. Operands straight from
// global (both contiguous bf16x8 by construction); no LDS.
__global__ __launch_bounds__(256)
void mix_mfma(const uint16_t* __restrict__ MhT, const uint16_t* __restrict__ Vt,
              uint16_t* __restrict__ out)
{
    const int h = blockIdx.x, b = blockIdx.y;
    const int tid  = threadIdx.x;
    const int lane = tid & 63;
    const int m_   = lane & 15;
    const int kg   = lane >> 4;
    const int w    = tid >> 6;          // 0..3 -> t-rows w*32..w*32+31

    const uint16_t* Abase = MhT + (size_t)h * MSL_ * MSL_;
    const uint16_t* Bbase = Vt + ((size_t)b * NH_ + h) * DH_ * MSL_;

    f32x4 acc[2][4] = {};
#pragma unroll
    for (int k0 = 0; k0 < MSL_; k0 += 32) {
        bf16x8 a[2], bf[4];
#pragma unroll
        for (int i = 0; i < 2; ++i)
            a[i] = *reinterpret_cast<const bf16x8*>(
                &Abase[(size_t)(w * 32 + i * 16 + m_) * MSL_ + k0 + kg * 8]);
#pragma unroll
        for (int j = 0; j < 4; ++j)
            bf[j] = *reinterpret_cast<const bf16x8*>(
                &Bbase[(size_t)(j * 16 + m_) * MSL_ + k0 + kg * 8]);
#pragma unroll
        for (int i = 0; i < 2; ++i)
#pragma unroll
            for (int j = 0; j < 4; ++j)
                acc[i][j] = __builtin_amdgcn_mfma_f32_16x16x32_bf16(
                    a[i], bf[j], acc[i][j], 0, 0, 0);
    }

    // out standard layout: row = b*128 + t, col = h*64 + d
#pragma unroll
    for (int i = 0; i < 2; ++i) {
#pragma unroll
        for (int j = 0; j < 4; ++j) {
            const int t0 = w * 32 + i * 16 + kg * 4;
            const int dd = j * 16 + m_;
#pragma unroll
            for (int r = 0; r < 4; ++r)
                out[(size_t)(b * MSL_ + t0 + r) * D_ + h * DH_ + dd] =
                    f2b(acc[i][j][r]);
        }
    }
}

// ---------------- Classifier ----------------
__global__ void cls_kernel(const uint16_t* __restrict__ H, const float* __restrict__ W,
                           const float* __restrict__ bias, float* __restrict__ out)
{
    const int b = blockIdx.x;
    const int lane = threadIdx.x;
    const uint16_t* row = H + (size_t)b * MSL_ * D_;
    float s0 = 0.f, s1 = 0.f;
    for (int d = lane; d < D_; d += 64) {
        const float xv = b2f(row[d]);
        s0 += xv * W[d];
        s1 += xv * W[D_ + d];
    }
#pragma unroll
    for (int off = 32; off > 0; off >>= 1) {
        s0 += __shfl_down(s0, off);
        s1 += __shfl_down(s1, off);
    }
    if (lane == 0) {
        out[b * 2 + 0] = s0 + bias[0];
        out[b * 2 + 1] = s1 + bias[1];
    }
}

extern "C" void kernel_launch(void* const* d_in, const int* in_sizes, int n_in,
                              void* d_out, int out_size, void* d_ws, size_t ws_size,
                              hipStream_t stream)
{
    const float* x     = (const float*)d_in[0];
    const float* M0    = (const float*)d_in[1];
    const float* M1    = (const float*)d_in[2];
    const float* Wv_w  = (const float*)d_in[3];
    const float* Wv_b  = (const float*)d_in[4];
    const float* d0_w  = (const float*)d_in[5];
    const float* d0_b  = (const float*)d_in[6];
    const float* lnw   = (const float*)d_in[7];
    const float* lnb   = (const float*)d_in[8];
    const float* ff0_w = (const float*)d_in[9];
    const float* ff0_b = (const float*)d_in[10];
    const float* ff1_w = (const float*)d_in[11];
    const float* ff1_b = (const float*)d_in[12];
    const float* lnffw = (const float*)d_in[13];
    const float* lnffb = (const float*)d_in[14];
    const float* Wv1_w = (const float*)d_in[15];
    const float* Wv1_b = (const float*)d_in[16];
    const float* d01_w = (const float*)d_in[17];
    const float* d01_b = (const float*)d_in[18];
    const float* lnw1  = (const float*)d_in[19];
    const float* lnb1  = (const float*)d_in[20];
    const float* ff01_w = (const float*)d_in[21];
    const float* ff01_b = (const float*)d_in[22];
    const float* ff11_w = (const float*)d_in[23];
    const float* ff11_b = (const float*)d_in[24];
    const float* lnffw1 = (const float*)d_in[25];
    const float* lnffb1 = (const float*)d_in[26];
    const float* cls_w  = (const float*)d_in[27];
    const float* cls_b  = (const float*)d_in[28];

    // ---- workspace layout (ushort elements) ----
    const size_t NB = (size_t)ROWS_ * D_;           // 12,582,912
    const size_t WTOT = 2ull * (2ull * D_ * D_ + 2ull * DI_ * D_);  // 11,796,480
    uint16_t* A0 = (uint16_t*)d_ws;
    uint16_t* A1 = A0 + NB;
    uint16_t* A2 = A1 + NB;
    uint16_t* wp = A2 + NB;
    uint16_t* bWv[2], *bD0[2], *bF0[2], *bF1[2];
    for (int blk = 0; blk < 2; ++blk) {
        bWv[blk] = wp; wp += (size_t)D_ * D_;
        bD0[blk] = wp; wp += (size_t)D_ * D_;
        bF0[blk] = wp; wp += (size_t)DI_ * D_;
        bF1[blk] = wp; wp += (size_t)D_ * DI_;
    }
    const size_t used_alias = (3ull * NB + WTOT) * sizeof(uint16_t);
    // FULL needs F (4*NB) + MhT (2*MT_SZ) after the weights.
    const size_t need_full  = used_alias + (4ull * NB + 2ull * MT_SZ) * sizeof(uint16_t);
    const bool full = (ws_size >= need_full);
    uint16_t* F  = full ? wp : A0;                  // FULL: dedicated; ALIAS: [A0;A1]
    uint16_t* mt = full ? (wp + 4ull * NB) : wp;    // MhT[2][12][128][128]
    const int CH = full ? ROWS_ : (ROWS_ / 2);      // 16384 or 8192 (both %256==0)

    auto cvt = [&](const float* in, uint16_t* out, size_t n) {
        const int n4 = (int)(n / 4);
        cvt_f32_bf16<<<dim3((n4 + 255) / 256), dim3(256), 0, stream>>>(in, out, n4);
    };

    cvt(x, A2, NB);
    cvt(Wv_w,  bWv[0], (size_t)D_ * D_);
    cvt(d0_w,  bD0[0], (size_t)D_ * D_);
    cvt(ff0_w, bF0[0], (size_t)DI_ * D_);
    cvt(ff1_w, bF1[0], (size_t)D_ * DI_);
    cvt(Wv1_w, bWv[1], (size_t)D_ * D_);
    cvt(d01_w, bD0[1], (size_t)D_ * D_);
    cvt(ff01_w, bF0[1], (size_t)DI_ * D_);
    cvt(ff11_w, bF1[1], (size_t)D_ * DI_);
    mtrans<<<dim3(NH_, 16), dim3(256), 0, stream>>>(M0, mt);
    mtrans<<<dim3(NH_, 16), dim3(256), 0, stream>>>(M1, mt + MT_SZ);

    const dim3 blk256(256);
    const dim3 blk512(512);

    auto gemm = [&](int EPI, const uint16_t* Ain, const uint16_t* Bw,
                    const float* bias, const float* sc, const float* sh,
                    uint16_t* Cout, int M, int N, int K) {
        const int gx = N / 256;
        const dim3 grid(gx * (M / 256));
        if (EPI == 0)
            gemm_bf16<0, 0><<<grid, blk512, 0, stream>>>(Ain, Bw, bias, sc, sh, Cout, M, N, K, gx);
        else if (EPI == 1)
            gemm_bf16<1, 0><<<grid, blk512, 0, stream>>>(Ain, Bw, bias, sc, sh, Cout, M, N, K, gx);
        else
            gemm_bf16<2, 0><<<grid, blk512, 0, stream>>>(Ain, Bw, bias, sc, sh, Cout, M, N, K, gx);
    };

    // Per transformer block (input & output = A2):
    //   V(TRANSV): A2 -> A0 (Vt layout) ; mix_mfma: A0 -> A1 (standard) ;
    //   dense0: A1 -> A2 ; FFN chunks on A2 (A0, A1 dead).
    auto run_block = [&](int bi,
                         const float* wv_b, const float* db,
                         const float* lw, const float* lb,
                         const float* f0b, const float* f1b,
                         const float* lfw, const float* lfb) {
        gemm_bf16<0, 1><<<dim3((D_ / 256) * (ROWS_ / 256)), blk512, 0, stream>>>(
            A2, bWv[bi], wv_b, nullptr, nullptr, A0, ROWS_, D_, D_, D_ / 256);
        mix_mfma<<<dim3(NH_, BS_), blk256, 0, stream>>>(mt + (size_t)bi * MT_SZ, A0, A1);
        gemm(1, A1, bD0[bi], db, lw, lb, A2, ROWS_, D_, D_);
        for (int c = 0; c < ROWS_; c += CH) {
            gemm(2, A2 + (size_t)c * D_, bF0[bi], f0b, nullptr, nullptr, F, CH, DI_, D_);
            gemm(1, F, bF1[bi], f1b, lfw, lfb, A2 + (size_t)c * D_, CH, D_, DI_);
        }
    };

    run_block(0, Wv_b, d0_b, lnw, lnb, ff0_b, ff1_b, lnffw, lnffb);
    run_block(1, Wv1_b, d01_b, lnw1, lnb1, ff01_b, ff11_b, lnffw1, lnffb1);

    cls_kernel<<<dim3(BS_), dim3(64), 0, stream>>>(A2, cls_w, cls_b, (float*)d_out);
}